// Round 2
// baseline (54.430 us; speedup 1.0000x reference)
//
#include <hip/hip_runtime.h>
#include <math.h>

// MixedFeatureEmbedder: out[b, f, :] for f even = x[b,f]*W_num[f/2,:] + b_num[f/2,:]
//                       for f odd  = emb_tables[f/2, clip(rint(nan_to_num(x[b,f])),0,99), :]
// Shapes: x (8192,64) f32, W_num/b_num (32,128) f32, emb_tables (32,100,128) f32,
// out (8192,64,128) f32 = 256 MiB -> write-BW bound (fill kernels: ~6.9 TB/s ceiling).
//
// R1 changes vs R0 (54 us):
//  - grid-stride loop: 2048 blocks, each 32-lane group loops ~32 rows (amortize wave setup)
//  - __builtin_nontemporal_store for the output stream (don't evict emb tables from L2)

#define TOKEN_DIM 128
#define N_FEAT 64
#define CARD 100

typedef float f32x4 __attribute__((ext_vector_type(4)));

__global__ __launch_bounds__(256) void mixed_embed_kernel(
    const float* __restrict__ x,
    const f32x4* __restrict__ W_num,
    const f32x4* __restrict__ b_num,
    const f32x4* __restrict__ emb,
    f32x4* __restrict__ out,
    int n_rows)
{
    const int lane    = threadIdx.x & 31;
    const int group0  = blockIdx.x * 8 + (threadIdx.x >> 5);
    const int ngroups = gridDim.x * 8;

    for (int row = group0; row < n_rows; row += ngroups) {
        const int f  = row & (N_FEAT - 1);   // feature index (x is [BATCH][64], row = b*64+f)
        const int f2 = f >> 1;

        const float xv = x[row];

        f32x4 r;
        if ((f & 1) == 0) {
            // numeric: out = x * W + b
            const f32x4 w  = W_num[f2 * (TOKEN_DIM/4) + lane];
            const f32x4 bb = b_num[f2 * (TOKEN_DIM/4) + lane];
            r.x = fmaf(xv, w.x, bb.x);
            r.y = fmaf(xv, w.y, bb.y);
            r.z = fmaf(xv, w.z, bb.z);
            r.w = fmaf(xv, w.w, bb.w);
        } else {
            // categorical: embedding gather
            float xc = isnan(xv) ? 0.0f : xv;
            float ridx = rintf(xc);          // round half-to-even, matches jnp.round
            ridx = fminf(fmaxf(ridx, 0.0f), (float)(CARD - 1));
            const int idx = (int)ridx;
            r = emb[(f2 * CARD + idx) * (TOKEN_DIM/4) + lane];
        }

        // write-only 256 MiB stream: bypass cache so emb tables stay L2-resident
        __builtin_nontemporal_store(r, out + row * (TOKEN_DIM/4) + lane);
    }
}

extern "C" void kernel_launch(void* const* d_in, const int* in_sizes, int n_in,
                              void* d_out, int out_size, void* d_ws, size_t ws_size,
                              hipStream_t stream) {
    const float* x     = (const float*)d_in[0];
    const f32x4* W_num = (const f32x4*)d_in[1];
    const f32x4* b_num = (const f32x4*)d_in[2];
    const f32x4* emb   = (const f32x4*)d_in[3];
    f32x4* out = (f32x4*)d_out;

    const int batch  = in_sizes[0] / N_FEAT;      // 8192
    const int n_rows = batch * N_FEAT;            // 524288

    const int blocks = 2048;                      // grid-stride; ~32 rows per 32-lane group
    mixed_embed_kernel<<<blocks, 256, 0, stream>>>(x, W_num, b_num, emb, out, n_rows);
}